// Round 8
// baseline (168.577 us; speedup 1.0000x reference)
//
#include <hip/hip_runtime.h>
#include <hip/hip_bf16.h>
#include <stdint.h>

// CRF nllh = sum_b (logZ_b - score_b).   TWO graph nodes: zero_kernel + crf.
// logZ via chunked parallel scan in probability domain:
//   alpha_t = alpha_{t-1} * Q_t,  Q_t[i][j] = exp(trans[i][j]/w_{t-1} + em_t[j])
// 32 chunks of 64 steps; chunk products via 32x32x16 bf16 MFMA pairs
// (X <- Q^T X, K=32 via C-chaining), sigma k-permutation folded into A-side
// constants, Schraudolph bf16-bits Q build with v_pk_fma_f32.
//
// R22/R23 (identical resubmit; R23 bench = infra "container failed twice"):
// PER-BATCH FUSION with in-LDS combine.
// Evidence: R17 showed a trivial 2nd node adds ~0 overhead (199.7 = 144.4 +
// 1.5 + 53.8 fixed), but two-kernel rounds carry ~35us MORE than
// chunk + 54 fixed -- an inter-node dependency gap invariant to combine
// content (R16 tree rewrite: only -8us; R21 XCD-local reads: 0). So fuse,
// but with a GOOD tail (R17's 16-block serial-global tail cost 67us).
// New structure: 256 blocks (one per batch) x 512 thr (8 waves). Wave w
// computes chunks 4w..4w+3 of batch b (same ILP=4 step4 stream; per-chain
// t-ranges; 8 waves/CU unchanged), stores X to LDS [16][36] (pad -> <=2-way
// bank conflicts). One barrier, then R16's tree combine IN-BLOCK: 8 waves x
// 4 MFMA products from LDS (same v_perm A-build), P->LDS, wave 0 does 8
// matvecs + t=0 terms + score; last-arrival block reduces res[] -> out.
// Rescale offsets stay in registers (offs array deleted); score via LDS
// (scoreP deleted); mats global buffer (16.8MB x2 traffic) deleted.
// Chunk 31 has 63 steps: per-wave G fast groups (G=7 for wave 7) + general
// tail of <=8 mask-guarded steps => barrier imbalance ~1%.
// Static LDS 110.7KB < 160KB gfx950 limit; no spin loops (hang-free).
//
// Negative results (do NOT revisit): ILP=8 spills; CHUNKS=64 -25%; spin
// barrier +140us; cross-wave TLP < in-wave ILP; 16-block serial-global
// fused tail (R17, +30us); depth-4 combine prefetch ring on global -30us;
// VALU-count cuts beyond pk_fma (loop is stall-bound, R19); XCD-local
// combine batch swizzle (R21, neutral).

#define T_DIM 2048
#define B_DIM 256
#define M_DIM 32
#define CHUNKS 32
#define CLEN 64
#define KSC 184.6649652337873f      /* 128 / ln2 */
#define SBIAS2 12599160.66f         /* 2^23 + 127*128 - 7.34 (log-mean center) */

typedef __attribute__((ext_vector_type(8))) short short8;
typedef __attribute__((ext_vector_type(16))) float f32x16;
typedef __attribute__((ext_vector_type(2))) float f32x2;

__device__ __forceinline__ int pack_bf16(float lo, float hi) {
  union { float f; uint32_t u; } a, b;
  a.f = lo; b.f = hi;
  // result = bf16(lo) | bf16(hi)<<16 (truncation rounding)
  return (int)__builtin_amdgcn_perm(b.u, a.u, 0x07060302u);
}

__device__ __forceinline__ int pack_lo16(int lo, int hi) {
  // (lo & 0xffff) | (hi << 16)
  return (int)__builtin_amdgcn_perm((uint32_t)hi, (uint32_t)lo, 0x05040100u);
}

__device__ __forceinline__ float bcast_lane(float v, int idx) {
  // wave-uniform broadcast: v_readlane -> SGPR (folds as scalar operand)
  return __int_as_float(__builtin_amdgcn_readlane(__float_as_int(v), idx));
}

// node 0: zero the arrival counter (graph edge orders it before crf_kernel)
__global__ void zero_kernel(uint32_t* __restrict__ ctrl) {
  if (threadIdx.x == 0) ctrl[0] = 0;
}

// ---------------- fused: chunk products + in-LDS tree combine ----------------
// One block per batch b. 8 waves; wave w owns chunks 4w..4w+3 as ILP chains.
__global__ __launch_bounds__(512, 1) void crf_kernel(
    const float* __restrict__ em, const int* __restrict__ tags,
    const float* __restrict__ wt, const int* __restrict__ mask,
    const float* __restrict__ trans, const float* __restrict__ startt,
    const float* __restrict__ endt, float* __restrict__ res,
    uint32_t* __restrict__ ctrl, float* __restrict__ out)
{
  const float INV_LN2 = 1.44269504088896340736f;
  const float LN2 = 0.69314718055994530942f;
  // chunk matrices as packed bf16 row-pairs: [chunk][pair][col], col pad 36
  __shared__ __align__(16) uint32_t matsL[CHUNKS][16][36];   // 73,728 B
  __shared__ __align__(16) float PL[8][32][36];              // 36,864 B
  __shared__ float logw[8];
  __shared__ float scoreW[8];

  int tid = threadIdx.x;
  int lane = tid & 63;
  int w = tid >> 6;         // wave 0..7
  int h = lane >> 5;        // wave half
  int r = lane & 31;        // A-row / B-col / D-col index
  int b = blockIdx.x;

  // A-side transition constants with the k-permutation sigma folded in:
  // sigma1(8h+j) = (j<4 ? j : j+4) + 4h ; sigma2 = sigma1 + 16
  // Stored as float2 pairs (qf[2u],qf[2u+1]) to feed v_pk_fma_f32.
  f32x2 tp2[8];
#pragma unroll
  for (int u = 0; u < 4; ++u) {
    int j0 = 2 * u, j1 = 2 * u + 1;
    int row0 = ((j0 < 4) ? j0 : j0 + 4) + 4 * h;
    int row1 = ((j1 < 4) ? j1 : j1 + 4) + 4 * h;
    tp2[u][0]     = trans[row0 * 32 + r] * KSC;
    tp2[u][1]     = trans[row1 * 32 + r] * KSC;
    tp2[4 + u][0] = trans[(row0 + 16) * 32 + r] * KSC;
    tp2[4 + u][1] = trans[(row1 + 16) * 32 + r] * KSC;
  }

  // per-chain chunk geometry + hoisted scalars (lane s <-> step t0c+s)
  int t0c[4], lenc[4];
  float rwv[4];
  uint64_t mk[4];
#pragma unroll
  for (int ch = 0; ch < 4; ++ch) {
    int c = 4 * w + ch;
    t0c[ch] = 1 + c * CLEN;
    int t1 = t0c[ch] + CLEN; if (t1 > T_DIM) t1 = T_DIM;
    lenc[ch] = t1 - t0c[ch];
    int tw = t0c[ch] - 1 + lane; if (tw > T_DIM - 1) tw = T_DIM - 1;
    int tm = t0c[ch] + lane;     if (tm > T_DIM - 1) tm = T_DIM - 1;
    rwv[ch] = __builtin_amdgcn_rcpf(wt[tw * B_DIM + b]);
    uint64_t valid = (lenc[ch] >= 64) ? ~0ull : ((1ull << lenc[ch]) - 1ull);
    mk[ch] = __ballot(mask[tm * B_DIM + b] != 0) & valid;
  }

  // X = identity in 32x32 D/C layout: reg p holds row (p&3)+8*(p>>2)+4h, col r
  f32x16 X[4], z;
#pragma unroll
  for (int p = 0; p < 16; ++p) {
    float v = (((p & 3) + 8 * (p >> 2) + 4 * h) == r) ? 1.f : 0.f;
    X[0][p] = v; X[1][p] = v; X[2][p] = v; X[3][p] = v;
    z[p] = 0.f;
  }
  float off2[4] = {0.f, 0.f, 0.f, 0.f};

  // phased 4-chain step: A-builds (v_pk_fma_f32), B-packs, MFMA1 x4, MFMA2 x4
  auto step4 = [&](const float* e4, int s) {
    float rw0 = bcast_lane(rwv[0], s), rw1 = bcast_lane(rwv[1], s);
    float rw2 = bcast_lane(rwv[2], s), rw3 = bcast_lane(rwv[3], s);
    float rw[4] = {rw0, rw1, rw2, rw3};
    union { int i[4]; short8 s8; } af1[4], af2[4], b1[4], b2[4];
#pragma unroll
    for (int ch = 0; ch < 4; ++ch) {
      float e = fmaf(e4[ch], KSC, SBIAS2);
      f32x2 e2 = {e, e}, rwp = {rw[ch], rw[ch]};
#pragma unroll
      for (int u = 0; u < 4; ++u) {
        union { f32x2 v; int i[2]; } qa, qb;
        qa.v = __builtin_elementwise_fma(tp2[u],     rwp, e2);
        qb.v = __builtin_elementwise_fma(tp2[4 + u], rwp, e2);
        af1[ch].i[u] = pack_lo16(qa.i[0], qa.i[1]);
        af2[ch].i[u] = pack_lo16(qb.i[0], qb.i[1]);
      }
    }
#pragma unroll
    for (int ch = 0; ch < 4; ++ch)
#pragma unroll
      for (int u = 0; u < 4; ++u) {
        b1[ch].i[u] = pack_bf16(X[ch][2 * u],     X[ch][2 * u + 1]);
        b2[ch].i[u] = pack_bf16(X[ch][8 + 2 * u], X[ch][8 + 2 * u + 1]);
      }
    f32x16 d[4];
#pragma unroll
    for (int ch = 0; ch < 4; ++ch)
      d[ch] = __builtin_amdgcn_mfma_f32_32x32x16_bf16(af1[ch].s8, b1[ch].s8, z, 0, 0, 0);
#pragma unroll
    for (int ch = 0; ch < 4; ++ch)
      X[ch] = __builtin_amdgcn_mfma_f32_32x32x16_bf16(af2[ch].s8, b2[ch].s8, d[ch], 0, 0, 0);
  };

  auto stepOne = [&](f32x16& Xc, float e_em, float rw) {
    float e = fmaf(e_em, KSC, SBIAS2);
    f32x2 e2 = {e, e}, rwp = {rw, rw};
    union { int i[4]; short8 s8; } af1, af2, b1_, b2_;
#pragma unroll
    for (int u = 0; u < 4; ++u) {
      union { f32x2 v; int i[2]; } qa, qb;
      qa.v = __builtin_elementwise_fma(tp2[u],     rwp, e2);
      qb.v = __builtin_elementwise_fma(tp2[4 + u], rwp, e2);
      af1.i[u] = pack_lo16(qa.i[0], qa.i[1]);
      af2.i[u] = pack_lo16(qb.i[0], qb.i[1]);
      b1_.i[u] = pack_bf16(Xc[2 * u],     Xc[2 * u + 1]);
      b2_.i[u] = pack_bf16(Xc[8 + 2 * u], Xc[8 + 2 * u + 1]);
    }
    f32x16 d = __builtin_amdgcn_mfma_f32_32x32x16_bf16(af1.s8, b1_.s8, z, 0, 0, 0);
    Xc = __builtin_amdgcn_mfma_f32_32x32x16_bf16(af2.s8, b2_.s8, d, 0, 0, 0);
  };

  auto rescale = [&](f32x16& Xc, float& o2) {
    float mx = Xc[0];
#pragma unroll
    for (int u = 1; u < 16; ++u) mx = fmaxf(mx, Xc[u]);
#pragma unroll
    for (int off = 1; off < 64; off <<= 1) mx = fmaxf(mx, __shfl_xor(mx, off));
    float sc = __builtin_amdgcn_rcpf(mx);
    o2 += __builtin_amdgcn_logf(mx);  // log2
#pragma unroll
    for (int u = 0; u < 16; ++u) Xc[u] *= sc;
  };

  // G full fast groups (no mask checks inside), then a general guarded tail.
  int minLen = lenc[0];
  if (lenc[1] < minLen) minLen = lenc[1];
  if (lenc[2] < minLen) minLen = lenc[2];
  if (lenc[3] < minLen) minLen = lenc[3];
  int Gc = minLen >> 3;
  bool allFull = true;
#pragma unroll
  for (int ch = 0; ch < 4; ++ch) {
    uint64_t need = (8 * Gc >= 64) ? ~0ull : ((1ull << (8 * Gc)) - 1ull);
    allFull = allFull && ((mk[ch] & need) == need);
  }
  int G = allFull ? Gc : 0;

  if (G > 0) {
    // ============ FAST GROUPS: branch-free, 8 steps each ============
    float e[4][4], n[4][4];
#pragma unroll
    for (int ch = 0; ch < 4; ++ch)
#pragma unroll
      for (int u = 0; u < 4; ++u) {
        int tt = t0c[ch] + 2 * u + h; if (tt > T_DIM - 1) tt = T_DIM - 1;
        e[ch][u] = em[((size_t)(tt * B_DIM + b)) * 32 + r];
      }
    for (int g = 0; g < G; ++g) {
#pragma unroll
      for (int ch = 0; ch < 4; ++ch)
#pragma unroll
        for (int u = 0; u < 4; ++u) {
          int tt = t0c[ch] + 8 * (g + 1) + 2 * u + h;
          if (tt > T_DIM - 1) tt = T_DIM - 1;
          n[ch][u] = em[((size_t)(tt * B_DIM + b)) * 32 + r];
        }
#pragma unroll
      for (int u = 0; u < 4; ++u) {
        int sA = 8 * g + 2 * u, sB = sA + 1;
        float eA[4], eB[4];
#pragma unroll
        for (int ch = 0; ch < 4; ++ch) {
          float sw = __shfl_xor(e[ch][u], 32);
          eA[ch] = h ? sw : e[ch][u];
          eB[ch] = h ? e[ch][u] : sw;
        }
        step4(eA, sA);
        step4(eB, sB);
      }
#pragma unroll
      for (int ch = 0; ch < 4; ++ch) rescale(X[ch], off2[ch]);
#pragma unroll
      for (int ch = 0; ch < 4; ++ch)
#pragma unroll
        for (int u = 0; u < 4; ++u) e[ch][u] = n[ch][u];
    }
  }
  if (G < 8) {
    // ============ GENERAL TAIL from step 8G: per-step mask guards ============
    int s0 = 8 * G;
    float emv[4], emp[4];
#pragma unroll
    for (int ch = 0; ch < 4; ++ch) {
      int tv = t0c[ch] + s0 + h;     if (tv > T_DIM - 1) tv = T_DIM - 1;
      int tp = t0c[ch] + s0 + 2 + h; if (tp > T_DIM - 1) tp = T_DIM - 1;
      emv[ch] = em[((size_t)(tv * B_DIM + b)) * 32 + r];
      emp[ch] = em[((size_t)(tp * B_DIM + b)) * 32 + r];
    }
    for (int it = 4 * G; it < CLEN / 2; ++it) {
      float emn[4];
#pragma unroll
      for (int ch = 0; ch < 4; ++ch) {
        int tn = t0c[ch] + 2 * it + 4 + h; if (tn > T_DIM - 1) tn = T_DIM - 1;
        emn[ch] = em[((size_t)(tn * B_DIM + b)) * 32 + r];
      }
      int sA = 2 * it, sB = sA + 1;
#pragma unroll
      for (int ch = 0; ch < 4; ++ch) {
        float sw = __shfl_xor(emv[ch], 32);
        if ((mk[ch] >> sA) & 1)
          stepOne(X[ch], h ? sw : emv[ch], bcast_lane(rwv[ch], sA));
        if ((mk[ch] >> sB) & 1)
          stepOne(X[ch], h ? emv[ch] : sw, bcast_lane(rwv[ch], sB));
      }
      if ((it & 3) == 3) {
#pragma unroll
        for (int ch = 0; ch < 4; ++ch) rescale(X[ch], off2[ch]);
      }
#pragma unroll
      for (int ch = 0; ch < 4; ++ch) { emv[ch] = emp[ch]; emp[ch] = emn[ch]; }
    }
  }

  // store X to LDS as packed bf16 row-pairs: matsL[c][pair][col]
#pragma unroll
  for (int ch = 0; ch < 4; ++ch) {
    int c = 4 * w + ch;
#pragma unroll
    for (int u = 0; u < 8; ++u) {
      int pairIdx = (u & 1) + (u >> 1) * 4 + 2 * h;
      matsL[c][pairIdx][r] = (uint32_t)pack_bf16(X[ch][2 * u], X[ch][2 * u + 1]);
    }
  }

  // ---- score epilogue for t>=1 of batch b: 4 timesteps per thread ----
  float ssc = 0.f;
#pragma unroll
  for (int k = 0; k < 4; ++k) {
    int t = 1 + tid + 512 * k;
    if (t < T_DIM) {
      int mkc = mask[t * B_DIM + b];
      int mkn = (t + 1 < T_DIM) ? mask[(t + 1) * B_DIM + b] : 0;
      int tg  = mkc ? tags[t * B_DIM + b] : 1;
      int mkp = mask[(t - 1) * B_DIM + b];
      int tgp = mkp ? tags[(t - 1) * B_DIM + b] : 1;
      if (mkc)
        ssc += em[(size_t)(t * B_DIM + b) * 32 + tg]
             + trans[tgp * 32 + tg] * __builtin_amdgcn_rcpf(wt[(t - 1) * B_DIM + b]);
      if (mkc && !mkn) ssc += endt[tg];
    }
  }
#pragma unroll
  for (int off = 32; off; off >>= 1) ssc += __shfl_xor(ssc, off);
  if (lane == 0) scoreW[w] = ssc;

  __syncthreads();   // all chunk matrices + score partials visible

  // ======== Phase A: wave w computes P_w = X_{4w+3}..X_{4w} from LDS ========
  // Lane needs row r, cols sigma1/2(8h+j): 4 uint4 LDS reads at u32 offsets
  // (r>>1)*36 + {4h, 8+4h, 16+4h, 24+4h}; 16-bit half by r&1 via v_perm.
  {
    uint32_t rsel = (r & 1) ? 0x07060302u : 0x05040100u;
    f32x16 P;
#pragma unroll
    for (int p = 0; p < 16; ++p)
      P[p] = ((((p & 3) + 8 * (p >> 2) + 4 * h) == r) ? 1.f : 0.f);
    float lw = off2[0] + off2[1] + off2[2] + off2[3];

#pragma unroll
    for (int i = 0; i < 4; ++i) {
      const uint4* mb = (const uint4*)(&matsL[4 * w + i][r >> 1][0]);
      uint4 A0 = mb[h], A1 = mb[2 + h], A2 = mb[4 + h], A3 = mb[6 + h];
      union { int i4[4]; short8 s8; } af1, af2, b1, b2;
      af1.i4[0] = (int)__builtin_amdgcn_perm(A0.y, A0.x, rsel);
      af1.i4[1] = (int)__builtin_amdgcn_perm(A0.w, A0.z, rsel);
      af1.i4[2] = (int)__builtin_amdgcn_perm(A1.y, A1.x, rsel);
      af1.i4[3] = (int)__builtin_amdgcn_perm(A1.w, A1.z, rsel);
      af2.i4[0] = (int)__builtin_amdgcn_perm(A2.y, A2.x, rsel);
      af2.i4[1] = (int)__builtin_amdgcn_perm(A2.w, A2.z, rsel);
      af2.i4[2] = (int)__builtin_amdgcn_perm(A3.y, A3.x, rsel);
      af2.i4[3] = (int)__builtin_amdgcn_perm(A3.w, A3.z, rsel);
#pragma unroll
      for (int u = 0; u < 4; ++u) {
        b1.i4[u] = pack_bf16(P[2 * u],     P[2 * u + 1]);
        b2.i4[u] = pack_bf16(P[8 + 2 * u], P[8 + 2 * u + 1]);
      }
      f32x16 d = __builtin_amdgcn_mfma_f32_32x32x16_bf16(af1.s8, b1.s8, z, 0, 0, 0);
      P = __builtin_amdgcn_mfma_f32_32x32x16_bf16(af2.s8, b2.s8, d, 0, 0, 0);
    }

    // normalize once (entries bounded by 32^4 in f32) and stage to LDS
    float mx = P[0];
#pragma unroll
    for (int p = 1; p < 16; ++p) mx = fmaxf(mx, P[p]);
#pragma unroll
    for (int off = 1; off < 64; off <<= 1) mx = fmaxf(mx, __shfl_xor(mx, off));
    float sc = __builtin_amdgcn_rcpf(mx);
    lw += __builtin_amdgcn_logf(mx);   // log2
#pragma unroll
    for (int p = 0; p < 16; ++p)
      PL[w][(p & 3) + 8 * (p >> 2) + 4 * h][r] = P[p] * sc;
    if (lane == 0) logw[w] = lw;
  }
  __syncthreads();

  if (tid >= 64) return;   // waves 1..7 done (no further barriers)

  // ======== Phase B (wave 0): 8 full matvecs + epilogue ========
  int j = r;
  float a0 = (startt[j] + em[(size_t)b * 32 + j]) * INV_LN2;  // log2 domain
  float cm = a0;
#pragma unroll
  for (int off = 1; off < 32; off <<= 1) cm = fmaxf(cm, __shfl_xor(cm, off));
  float av = __builtin_amdgcn_exp2f(a0 - cm);  // duplicated across halves
  float acc = cm + logw[0] + logw[1] + logw[2] + logw[3]
                 + logw[4] + logw[5] + logw[6] + logw[7];

#pragma unroll
  for (int wv = 0; wv < 8; ++wv) {
    const float4* Pr = (const float4*)&PL[wv][j][16 * h];
    float4 q0 = Pr[0], q1 = Pr[1], q2 = Pr[2], q3 = Pr[3];
    int cb = 16 * h;
    float s = fmaf(q0.x, __shfl(av, cb + 0),
              fmaf(q0.y, __shfl(av, cb + 1),
              fmaf(q0.z, __shfl(av, cb + 2),
                   q0.w * __shfl(av, cb + 3))));
    s = fmaf(q1.x, __shfl(av, cb + 4),
        fmaf(q1.y, __shfl(av, cb + 5),
        fmaf(q1.z, __shfl(av, cb + 6),
        fmaf(q1.w, __shfl(av, cb + 7), s))));
    s = fmaf(q2.x, __shfl(av, cb + 8),
        fmaf(q2.y, __shfl(av, cb + 9),
        fmaf(q2.z, __shfl(av, cb + 10),
        fmaf(q2.w, __shfl(av, cb + 11), s))));
    s = fmaf(q3.x, __shfl(av, cb + 12),
        fmaf(q3.y, __shfl(av, cb + 13),
        fmaf(q3.z, __shfl(av, cb + 14),
        fmaf(q3.w, __shfl(av, cb + 15), s))));
    float an = s + __shfl_xor(s, 32);          // combine the two column-halves
    float m2 = an;
#pragma unroll
    for (int off = 1; off < 32; off <<= 1) m2 = fmaxf(m2, __shfl_xor(m2, off));
    av = an * __builtin_amdgcn_rcpf(m2);
    acc += __builtin_amdgcn_logf(m2);          // log2
  }

  float sv = av * __builtin_amdgcn_exp2f(endt[j] * INV_LN2);
#pragma unroll
  for (int off = 1; off < 32; off <<= 1) sv += __shfl_xor(sv, off);
  if (lane == 0) {
    float logZ = (acc + __builtin_amdgcn_logf(sv)) * LN2;
    // t=0 gold-path score terms
    int mk0 = mask[b];
    int tg0 = mk0 ? tags[b] : 1;
    float s0 = startt[tg0] + (mk0 ? em[(size_t)b * 32 + tg0] : 0.f);
    int mk1 = mask[B_DIM + b];
    if (mk0 && !mk1) s0 += endt[tg0];
    float st = scoreW[0] + scoreW[1] + scoreW[2] + scoreW[3]
             + scoreW[4] + scoreW[5] + scoreW[6] + scoreW[7];
    res[b] = logZ - s0 - st;
  }

  // ---- last-block-done final reduction (no spinning) ----
  __builtin_amdgcn_fence(__ATOMIC_RELEASE, "agent");
  unsigned old = 0;
  if (lane == 0) old = atomicAdd(&ctrl[0], 1u);
  old = (unsigned)__shfl((int)old, 0);
  if (old == (unsigned)(B_DIM - 1)) {
    __builtin_amdgcn_fence(__ATOMIC_ACQUIRE, "agent");
    float s = 0.f;
#pragma unroll
    for (int k = 0; k < 4; ++k) s += res[lane + 64 * k];
#pragma unroll
    for (int off = 32; off; off >>= 1) s += __shfl_xor(s, off);
    if (lane == 0) out[0] = s;
  }
}

extern "C" void kernel_launch(void* const* d_in, const int* in_sizes, int n_in,
                              void* d_out, int out_size, void* d_ws, size_t ws_size,
                              hipStream_t stream) {
  const float* em   = (const float*)d_in[0];
  const int*   tags = (const int*)d_in[1];
  const float* wt   = (const float*)d_in[2];
  const int*   mask = (const int*)d_in[3];
  const float* tr   = (const float*)d_in[4];
  const float* stt  = (const float*)d_in[5];
  const float* ent  = (const float*)d_in[6];
  float* out = (float*)d_out;

  uint32_t* ctrl = (uint32_t*)d_ws;        // [0] = arrival counter
  float* res     = (float*)d_ws + 4;       // 256 floats

  zero_kernel<<<1, 64, 0, stream>>>(ctrl);
  crf_kernel<<<B_DIM, 512, 0, stream>>>(em, tags, wt, mask, tr, stt, ent,
                                        res, ctrl, out);
}